// Round 6
// baseline (573.246 us; speedup 1.0000x reference)
//
#include <hip/hip_runtime.h>
#include <hip/hip_bf16.h>

#define NN    65536
#define KDIM  1024
#define HDIM  256
#define NC    8
#define BM    64
#define NPH   32      // K phases of 32

typedef __bf16 bf16x8 __attribute__((ext_vector_type(8)));
typedef float  f32x4  __attribute__((ext_vector_type(4)));

static __device__ __forceinline__ unsigned short f2bf_rne(float f) {
    unsigned int u = __float_as_uint(f);
    unsigned int r = u + 0x7fffu + ((u >> 16) & 1u);
    return (unsigned short)(r >> 16);
}

static __device__ __forceinline__ unsigned long long pack4bf(float4 v) {
    return (unsigned long long)f2bf_rne(v.x)
         | ((unsigned long long)f2bf_rne(v.y) << 16)
         | ((unsigned long long)f2bf_rne(v.z) << 32)
         | ((unsigned long long)f2bf_rne(v.w) << 48);
}

// ---- Kernel 0: x fp32 -> bf16 in A-fragment-chunk order -------------------
// Reads x LINEARLY (DRAM-friendly); writes xb chunk (rb*128 + kb*4 + i)*64 + lane,
// lane = q*16 + l15, content = x[rb*64 + i*16 + l15][kb*32 + q*8 .. +8).
__global__ __launch_bounds__(256) void convert_kernel(
    const float* __restrict__ x, unsigned short* __restrict__ xb)
{
    __shared__ unsigned short tile[16 * 1032];   // 16 rows x 1024 bf16 (+8 pad)
    const int tid = threadIdx.x;
    const int B0  = blockIdx.x;                  // one 16-row slab
    const float* src = x + (size_t)B0 * 16 * KDIM;

    #pragma unroll 4
    for (int rep = 0; rep < 16; ++rep) {
        float4 v = *(const float4*)(src + (size_t)rep * KDIM + tid * 4);
        *(unsigned long long*)&tile[rep * 1032 + tid * 4] = pack4bf(v);
    }
    __syncthreads();

    const int rb = B0 >> 2, ii = B0 & 3;
    unsigned short* dstbase = xb + (size_t)rb * 65536 + ii * 512;
    #pragma unroll
    for (int wr = 0; wr < 8; ++wr) {
        int g    = wr * 256 + tid;
        int kb   = g >> 6, lane = g & 63;
        int q    = lane >> 4, l15 = lane & 15;
        ulonglong2 v = *(const ulonglong2*)&tile[l15 * 1032 + kb * 32 + q * 8];
        *(ulonglong2*)(dstbase + (size_t)kb * 2048 + lane * 8) = v;  // 1KB/wave contiguous
    }
}

// ---- Kernel 1: W1 fp32 -> bf16, B-fragment-linear layout + per-block hist --
// chunk ci = kb*1024 + wave*256 + j*64 + lane; content W1[n][k0..k0+7],
// n = wave*64 + j*16 + (lane&15), k0 = kb*32 + (lane>>4)*8
__global__ __launch_bounds__(256) void prep_kernel(
    const float* __restrict__ W1, unsigned short* __restrict__ W1b,
    const int* __restrict__ cid, int* __restrict__ cnt_partial)
{
    __shared__ int hcnt[NC];
    if (threadIdx.x < NC) hcnt[threadIdx.x] = 0;
    __syncthreads();

    const int gid  = blockIdx.x * 256 + threadIdx.x;   // 0..32767 chunks
    const int lane = gid & 63;
    const int j    = (gid >> 6) & 3;
    const int wv   = (gid >> 8) & 3;
    const int kb   = gid >> 10;
    const int n    = wv * 64 + j * 16 + (lane & 15);
    const int k0   = kb * 32 + (lane >> 4) * 8;
    const float* src = W1 + (size_t)n * KDIM + k0;
    float4 v0 = *(const float4*)(src);
    float4 v1 = *(const float4*)(src + 4);
    ulonglong2 pk;
    pk.x = pack4bf(v0);
    pk.y = pack4bf(v1);
    *(ulonglong2*)(W1b + (size_t)gid * 8) = pk;

    atomicAdd(&hcnt[cid[gid]], 1);                    // LDS atomics only
    atomicAdd(&hcnt[cid[gid + 32768]], 1);
    __syncthreads();
    if (threadIdx.x < NC)
        cnt_partial[blockIdx.x * NC + threadIdx.x] = hcnt[threadIdx.x];
}

// ---- Kernel 2: bf16 MFMA GEMM + ReLU + segment sum ------------------------
// A and B both direct global->register (xb L3-resident, W1b L2-resident),
// 1-phase register prefetch, NO barriers / NO LDS in the K-loop.
__global__ __launch_bounds__(256, 3) void gemm_kernel(
    const unsigned short* __restrict__ xb, const int* __restrict__ cid,
    const unsigned short* __restrict__ W1b, const float* __restrict__ b1,
    float* __restrict__ partial)
{
    __shared__ float lsums[HDIM * NC];                // 8 KB, [col][k]
    __shared__ int cids[BM];

    const int tid  = threadIdx.x;
    const int wave = tid >> 6;
    const int lane = tid & 63;
    const int l15  = lane & 15;
    const int q    = lane >> 4;
    const int rb   = blockIdx.x;
    const int row0 = rb * BM;

    for (int i = tid; i < HDIM * NC; i += 256) lsums[i] = 0.0f;
    if (tid < BM) cids[tid] = cid[row0 + tid];

    f32x4 acc[4][4];
    #pragma unroll
    for (int i = 0; i < 4; ++i)
        #pragma unroll
        for (int j = 0; j < 4; ++j)
            #pragma unroll
            for (int r = 0; r < 4; ++r) acc[i][j][r] = 0.0f;

    // per-lane bases (shorts). A(kb,i): ag + kb*2048 + i*512.  B(kb,j): bg + kb*8192 + j*512.
    const unsigned short* ag = xb  + (size_t)rb * 65536 + lane * 8;
    const unsigned short* bg = W1b + (size_t)wave * 2048 + lane * 8;

    bf16x8 cA[4], cB[4];
    #pragma unroll
    for (int i = 0; i < 4; ++i) cA[i] = *(const bf16x8*)(ag + i * 512);
    #pragma unroll
    for (int j = 0; j < 4; ++j) cB[j] = *(const bf16x8*)(bg + j * 512);

    #pragma unroll 2
    for (int kb = 0; kb < NPH; ++kb) {
        bf16x8 nA[4], nB[4];
        if (kb + 1 < NPH) {
            #pragma unroll
            for (int i = 0; i < 4; ++i)
                nA[i] = *(const bf16x8*)(ag + (size_t)(kb + 1) * 2048 + i * 512);
            #pragma unroll
            for (int j = 0; j < 4; ++j)
                nB[j] = *(const bf16x8*)(bg + (size_t)(kb + 1) * 8192 + j * 512);
        }
        #pragma unroll
        for (int i = 0; i < 4; ++i)
            #pragma unroll
            for (int j = 0; j < 4; ++j)
                acc[i][j] = __builtin_amdgcn_mfma_f32_16x16x32_bf16(cA[i], cB[j], acc[i][j], 0, 0, 0);
        #pragma unroll
        for (int i = 0; i < 4; ++i) { cA[i] = nA[i]; cB[i] = nB[i]; }
    }

    __syncthreads();   // lsums init visible
    // epilogue: bias + relu + per-cluster LDS accumulation ([col][k] layout)
    float b1v[4];
    #pragma unroll
    for (int j = 0; j < 4; ++j) b1v[j] = b1[wave * 64 + j * 16 + l15];

    #pragma unroll
    for (int i = 0; i < 4; ++i) {
        #pragma unroll
        for (int j = 0; j < 4; ++j) {
            const int col = wave * 64 + j * 16 + l15;
            #pragma unroll
            for (int r = 0; r < 4; ++r) {
                float v = fmaxf(acc[i][j][r] + b1v[j], 0.0f);
                int m = i * 16 + q * 4 + r;
                atomicAdd(&lsums[col * NC + cids[m]], v);
            }
        }
    }
    __syncthreads();
    // plain coalesced store of this block's partial sums (no global atomics)
    float* dst = partial + (size_t)rb * 2048 + tid * 8;
    *(f32x4*)dst       = *(const f32x4*)&lsums[tid * 8];
    *(f32x4*)(dst + 4) = *(const f32x4*)&lsums[tid * 8 + 4];
}

// ---- Kernel 3: reduce 1024 partials -> stage2[8][2048] (no atomics) -------
__global__ __launch_bounds__(256) void reduce_kernel(
    const float* __restrict__ partial, float* __restrict__ stage2)
{
    const int s  = blockIdx.x >> 3;   // pb-split 0..7 (128 blocks each)
    const int og = blockIdx.x & 7;    // output group
    const int o  = og * 256 + threadIdx.x;
    const float* p = partial + (size_t)s * 128 * 2048 + o;
    float a0=0,a1=0,a2=0,a3=0,a4=0,a5=0,a6=0,a7=0;
    #pragma unroll 4
    for (int pb = 0; pb < 128; pb += 8) {
        a0 += p[(size_t)(pb+0)*2048]; a1 += p[(size_t)(pb+1)*2048];
        a2 += p[(size_t)(pb+2)*2048]; a3 += p[(size_t)(pb+3)*2048];
        a4 += p[(size_t)(pb+4)*2048]; a5 += p[(size_t)(pb+5)*2048];
        a6 += p[(size_t)(pb+6)*2048]; a7 += p[(size_t)(pb+7)*2048];
    }
    stage2[(size_t)s * 2048 + o] = ((a0+a1)+(a2+a3)) + ((a4+a5)+(a6+a7));
}

// ---- Kernel 4: fused head: counts+mean -> Linear+ReLU -> gated attn -------
__global__ __launch_bounds__(256) void head_kernel(
    const float* __restrict__ stage2, const int* __restrict__ cnt_partial,
    const float* __restrict__ Wf, const float* __restrict__ bf1,
    const float* __restrict__ Wa, const float* __restrict__ ba,
    const float* __restrict__ Wb, const float* __restrict__ bb,
    const float* __restrict__ Wc, const float* __restrict__ bc,
    float* __restrict__ out)
{
    __shared__ float hcT[HDIM * NC];  // [d][k]
    __shared__ float hpT[HDIM * NC];  // [d][k]
    __shared__ float red[NC * 4];
    __shared__ int   cnt_s[256];
    __shared__ float cnt_f[NC];
    const int c = threadIdx.x;
    const int wave = c >> 6, lane = c & 63;

    // reduce counts: 128 blocks x 8 -> 8
    {
        int k = c & 7, g = c >> 3;                     // g 0..31
        const int* cp = cnt_partial + g * 32 + k;      // 4 blocks of 8
        cnt_s[c] = cp[0] + cp[8] + cp[16] + cp[24];
    }
    __syncthreads();
    if (c < NC) {
        int s = 0;
        #pragma unroll
        for (int g = 0; g < 32; ++g) s += cnt_s[g * 8 + c];
        cnt_f[c] = 1.0f / fmaxf((float)s, 1.0f);
    }
    __syncthreads();

    // final gsum reduce (8 stage2 slices) + mean
    {
        float a[NC] = {0,0,0,0,0,0,0,0};
        #pragma unroll
        for (int s = 0; s < 8; ++s) {
            f32x4 u0 = *(const f32x4*)&stage2[(size_t)s * 2048 + c * 8];
            f32x4 u1 = *(const f32x4*)&stage2[(size_t)s * 2048 + c * 8 + 4];
            a[0]+=u0[0]; a[1]+=u0[1]; a[2]+=u0[2]; a[3]+=u0[3];
            a[4]+=u1[0]; a[5]+=u1[1]; a[6]+=u1[2]; a[7]+=u1[3];
        }
        #pragma unroll
        for (int k = 0; k < NC; ++k) hcT[c * NC + k] = a[k] * cnt_f[k];
    }
    __syncthreads();

    // h_path[k][c] = relu(Wf[c,:] . hc[k,:] + bf[c])
    {
        float acc[NC];
        float bias = bf1[c];
        #pragma unroll
        for (int k = 0; k < NC; ++k) acc[k] = bias;
        const float4* wf4 = (const float4*)(Wf + (size_t)c * HDIM);
        for (int d4 = 0; d4 < 64; ++d4) {
            float4 w = wf4[d4];
            #pragma unroll
            for (int e = 0; e < 4; ++e) {
                float wd = (e == 0) ? w.x : (e == 1) ? w.y : (e == 2) ? w.z : w.w;
                const f32x4 h0 = *(const f32x4*)&hcT[(d4 * 4 + e) * NC];
                const f32x4 h1 = *(const f32x4*)&hcT[(d4 * 4 + e) * NC + 4];
                acc[0] += wd * h0[0]; acc[1] += wd * h0[1];
                acc[2] += wd * h0[2]; acc[3] += wd * h0[3];
                acc[4] += wd * h1[0]; acc[5] += wd * h1[1];
                acc[6] += wd * h1[2]; acc[7] += wd * h1[3];
            }
        }
        #pragma unroll
        for (int k = 0; k < NC; ++k) hpT[c * NC + k] = fmaxf(acc[k], 0.0f);
    }
    __syncthreads();

    // gated attention logits
    float za[NC], zb[NC];
    {
        float biasa = ba[c], biasb = bb[c];
        #pragma unroll
        for (int k = 0; k < NC; ++k) { za[k] = biasa; zb[k] = biasb; }
        const float4* wa4 = (const float4*)(Wa + (size_t)c * HDIM);
        const float4* wb4 = (const float4*)(Wb + (size_t)c * HDIM);
        for (int d4 = 0; d4 < 64; ++d4) {
            float4 wa = wa4[d4], wb = wb4[d4];
            #pragma unroll
            for (int e = 0; e < 4; ++e) {
                float wav = (e == 0) ? wa.x : (e == 1) ? wa.y : (e == 2) ? wa.z : wa.w;
                float wbv = (e == 0) ? wb.x : (e == 1) ? wb.y : (e == 2) ? wb.z : wb.w;
                const f32x4 h0 = *(const f32x4*)&hpT[(d4 * 4 + e) * NC];
                const f32x4 h1 = *(const f32x4*)&hpT[(d4 * 4 + e) * NC + 4];
                za[0] += wav * h0[0]; za[1] += wav * h0[1]; za[2] += wav * h0[2]; za[3] += wav * h0[3];
                za[4] += wav * h1[0]; za[5] += wav * h1[1]; za[6] += wav * h1[2]; za[7] += wav * h1[3];
                zb[0] += wbv * h0[0]; zb[1] += wbv * h0[1]; zb[2] += wbv * h0[2]; zb[3] += wbv * h0[3];
                zb[4] += wbv * h1[0]; zb[5] += wbv * h1[1]; zb[6] += wbv * h1[2]; zb[7] += wbv * h1[3];
            }
        }
    }
    float wcv = Wc[c];
    float v[NC];
    #pragma unroll
    for (int k = 0; k < NC; ++k) {
        float a = tanhf(za[k]);
        float g = 1.0f / (1.0f + expf(-zb[k]));
        v[k] = a * g * wcv;
    }
    #pragma unroll
    for (int k = 0; k < NC; ++k) {
        float s = v[k];
        #pragma unroll
        for (int off = 32; off > 0; off >>= 1) s += __shfl_down(s, off, 64);
        if (lane == 0) red[k * 4 + wave] = s;
    }
    __syncthreads();
    float logit[NC], m = -1e30f;
    #pragma unroll
    for (int k = 0; k < NC; ++k) {
        logit[k] = red[k * 4] + red[k * 4 + 1] + red[k * 4 + 2] + red[k * 4 + 3] + bc[0];
        m = fmaxf(m, logit[k]);
    }
    float s = 0.0f, ex[NC];
    #pragma unroll
    for (int k = 0; k < NC; ++k) { ex[k] = expf(logit[k] - m); s += ex[k]; }
    float inv = 1.0f / s;
    float o = 0.0f;
    #pragma unroll
    for (int k = 0; k < NC; ++k) o += ex[k] * inv * hpT[c * NC + k];
    out[c] = o;
}

extern "C" void kernel_launch(void* const* d_in, const int* in_sizes, int n_in,
                              void* d_out, int out_size, void* d_ws, size_t ws_size,
                              hipStream_t stream)
{
    (void)in_sizes; (void)n_in; (void)out_size; (void)ws_size;
    const float* x   = (const float*)d_in[0];
    const int*   cid = (const int*)  d_in[1];
    const float* W1  = (const float*)d_in[2];
    const float* b1  = (const float*)d_in[3];
    const float* Wf  = (const float*)d_in[4];
    const float* bfv = (const float*)d_in[5];
    const float* Wa  = (const float*)d_in[6];
    const float* ba  = (const float*)d_in[7];
    const float* Wb  = (const float*)d_in[8];
    const float* bb  = (const float*)d_in[9];
    const float* Wc  = (const float*)d_in[10];
    const float* bc  = (const float*)d_in[11];
    float* out = (float*)d_out;

    // workspace layout (~137 MB)
    unsigned short* W1b   = (unsigned short*)d_ws;                       // 512 KB
    int*   cnt_partial    = (int*)  ((char*)d_ws + 524288);              // 4 KB
    float* stage2         = (float*)((char*)d_ws + 528384);              // 64 KB
    float* partial        = (float*)((char*)d_ws + 593920);              // 8 MB
    unsigned short* xb    = (unsigned short*)((char*)d_ws + 8982528);    // 128 MB bf16

    hipLaunchKernelGGL(convert_kernel, dim3(4096),    dim3(256), 0, stream, x, xb);
    hipLaunchKernelGGL(prep_kernel,    dim3(128),     dim3(256), 0, stream, W1, W1b, cid, cnt_partial);
    hipLaunchKernelGGL(gemm_kernel,    dim3(NN / BM), dim3(256), 0, stream, xb, cid, W1b, b1, partial);
    hipLaunchKernelGGL(reduce_kernel,  dim3(64),      dim3(256), 0, stream, partial, stage2);
    hipLaunchKernelGGL(head_kernel,    dim3(1),       dim3(256), 0, stream,
                       stage2, cnt_partial, Wf, bfv, Wa, ba, Wb, bb, Wc, bc, out);
}